// Round 2
// baseline (12689.184 us; speedup 1.0000x reference)
//
#include <hip/hip_runtime.h>
#include <hip/hip_bf16.h>
#include <hip/hip_cooperative_groups.h>

namespace cg = cooperative_groups;

typedef __bf16 bf16x8 __attribute__((ext_vector_type(8)));
typedef float f32x4 __attribute__((ext_vector_type(4)));
typedef unsigned short u16;

// ---------- helpers ----------
__device__ __forceinline__ u16 f2bf(float f) {
  union { float f; unsigned int i; } c;
  c.f = f;
  unsigned int x = c.i;
  return (u16)((x + 0x7fffu + ((x >> 16) & 1u)) >> 16);  // RNE
}
__device__ __forceinline__ float sigm(float x) { return 1.f / (1.f + __expf(-x)); }
__device__ __forceinline__ float tanh_fast(float x) {
  float e2 = __expf(2.f * x);
  return 1.f - 2.f / (e2 + 1.f);
}

// ---------- fp32 -> bf16 (plain, vectorized) ----------
__global__ void cvt_f32_bf16_v4(const float* __restrict__ in, u16* __restrict__ out, int n4) {
  int stride = gridDim.x * blockDim.x;
  for (int i = blockIdx.x * blockDim.x + threadIdx.x; i < n4; i += stride) {
    float4 v = reinterpret_cast<const float4*>(in)[i];
    union { u16 u[4]; uint2 d; } o;
    o.u[0] = f2bf(v.x); o.u[1] = f2bf(v.y); o.u[2] = f2bf(v.z); o.u[3] = f2bf(v.w);
    reinterpret_cast<uint2*>(out)[i] = o.d;
  }
}

// ---------- x: [N=64][T=512][d=512] f32 -> [T][N][d] bf16 ----------
__global__ void cvt_x_transpose(const float* __restrict__ in, u16* __restrict__ out) {
  int i = blockIdx.x * blockDim.x + threadIdx.x;  // 0 .. 64*512*64-1
  if (i >= 64 * 512 * 64) return;
  int k8 = i & 63, t = (i >> 6) & 511, n = i >> 15;
  const float* src = in + ((size_t)(n * 512 + t) << 9) + (k8 << 3);
  float4 a = reinterpret_cast<const float4*>(src)[0];
  float4 b = reinterpret_cast<const float4*>(src)[1];
  union { u16 u[8]; uint4 d; } o;
  o.u[0] = f2bf(a.x); o.u[1] = f2bf(a.y); o.u[2] = f2bf(a.z); o.u[3] = f2bf(a.w);
  o.u[4] = f2bf(b.x); o.u[5] = f2bf(b.y); o.u[6] = f2bf(b.z); o.u[7] = f2bf(b.w);
  *reinterpret_cast<uint4*>(out + ((size_t)(t * 64 + n) << 9) + (k8 << 3)) = o.d;
}

// ---------- persistent LSTM: 128 blocks x 256 threads, 8 hidden units/block ----------
// Block b owns units j0=b*8 .. j0+7  (32 gate rows: local row l = g*8+u).
// LDS keeps w_hh slice [32][1024] and w_ih slice [32][512] stationary.
// Per step: gates(64x32) = h(64x1024) @ whh_sl^T + x_t(64x512) @ wih_sl^T  (MFMA, fp32 acc)
// then pointwise cell update; h double-buffered in global; one grid.sync per step.
__global__ void __launch_bounds__(256, 1) lstm_seq(
    const u16* __restrict__ xb,     // [512][64][512] bf16
    const u16* __restrict__ wib,    // [4096][512] bf16
    const u16* __restrict__ whb,    // [4096][1024] bf16
    u16* __restrict__ hbuf,         // [2][64][1024] bf16
    const float* __restrict__ b_ih, const float* __restrict__ b_hh,
    const float* __restrict__ fc_w, const float* __restrict__ fc_b,
    float* __restrict__ out) {
  __shared__ u16 wh[32][1032];     // 66048 B  (pad 8 u16 -> row stride 2064 B)
  __shared__ u16 wi[32][520];      // 33280 B
  __shared__ float gates[64][33];  // 8448 B   [batch][g*8+u]
  __shared__ float c_s[64][9];     // 2304 B
  __shared__ float bias_s[32];

  cg::grid_group grid = cg::this_grid();
  int b = blockIdx.x, t = threadIdx.x;
  int j0 = b << 3;

  // stage weight slices (once)
  for (int idx = t; idx < 32 * 128; idx += 256) {   // wh: 32 rows x 128 chunks
    int l = idx >> 7, c8 = idx & 127;
    int gr = ((l >> 3) << 10) + j0 + (l & 7);
    *(bf16x8*)(&wh[l][c8 * 8]) = *(const bf16x8*)(whb + ((size_t)gr << 10) + c8 * 8);
  }
  for (int idx = t; idx < 32 * 64; idx += 256) {    // wi: 32 rows x 64 chunks
    int l = idx >> 6, c8 = idx & 63;
    int gr = ((l >> 3) << 10) + j0 + (l & 7);
    *(bf16x8*)(&wi[l][c8 * 8]) = *(const bf16x8*)(wib + ((size_t)gr << 9) + c8 * 8);
  }
  if (t < 32) {
    int gr = ((t >> 3) << 10) + j0 + (t & 7);
    bias_s[t] = b_ih[gr] + b_hh[gr];
  }
  for (int idx = t; idx < 512; idx += 256) c_s[idx >> 3][idx & 7] = 0.f;
  // h buffer 0 = zeros (grid-wide, disjoint)
  { unsigned* h0 = (unsigned*)hbuf;                 // 64*1024*2 B = 32768 u32
    int idx = b * 256 + t;                          // 128*256 = 32768
    h0[idx] = 0u; }
  __syncthreads();
  grid.sync();

  int lane = t & 63, wave = t >> 6;
  int m0 = wave << 4;                 // wave's 16 batch rows
  int lr = lane & 15, lk8 = (lane >> 4) << 3;

  for (int step = 0; step < 512; ++step) {
    const u16* hr = hbuf + ((step & 1) << 16);
    u16* hw = hbuf + (((step + 1) & 1) << 16);
    const u16* xt = xb + ((size_t)step << 15);   // [64][512]

    f32x4 acc[2] = {};
    const u16* hbase = hr + ((m0 + lr) << 10) + lk8;
#pragma unroll 8
    for (int k = 0; k < 1024; k += 32) {
      bf16x8 a = *(const bf16x8*)(hbase + k);
      bf16x8 b0 = *(const bf16x8*)(&wh[lr][k + lk8]);
      bf16x8 b1 = *(const bf16x8*)(&wh[16 + lr][k + lk8]);
      acc[0] = __builtin_amdgcn_mfma_f32_16x16x32_bf16(a, b0, acc[0], 0, 0, 0);
      acc[1] = __builtin_amdgcn_mfma_f32_16x16x32_bf16(a, b1, acc[1], 0, 0, 0);
    }
    const u16* xbase = xt + ((m0 + lr) << 9) + lk8;
#pragma unroll 8
    for (int k = 0; k < 512; k += 32) {
      bf16x8 a = *(const bf16x8*)(xbase + k);
      bf16x8 b0 = *(const bf16x8*)(&wi[lr][k + lk8]);
      bf16x8 b1 = *(const bf16x8*)(&wi[16 + lr][k + lk8]);
      acc[0] = __builtin_amdgcn_mfma_f32_16x16x32_bf16(a, b0, acc[0], 0, 0, 0);
      acc[1] = __builtin_amdgcn_mfma_f32_16x16x32_bf16(a, b1, acc[1], 0, 0, 0);
    }
#pragma unroll
    for (int n = 0; n < 2; ++n)
#pragma unroll
      for (int q = 0; q < 4; ++q)
        gates[m0 + ((lane >> 4) << 2) + q][(n << 4) + lr] = acc[n][q];
    __syncthreads();

    // pointwise: 2 (batch,unit) pairs per thread
#pragma unroll
    for (int i = 0; i < 2; ++i) {
      int idx = t + (i << 8);
      int m = idx >> 3, u = idx & 7;
      float gi = gates[m][u]      + bias_s[u];
      float gf = gates[m][8 + u]  + bias_s[8 + u];
      float gg = gates[m][16 + u] + bias_s[16 + u];
      float go = gates[m][24 + u] + bias_s[24 + u];
      float ii = sigm(gi), ff = sigm(gf), tg = tanh_fast(gg), oo = sigm(go);
      float cn = ff * c_s[m][u] + ii * tg;
      c_s[m][u] = cn;
      hw[(m << 10) + j0 + u] = f2bf(oo * tanh_fast(cn));
    }
    grid.sync();
  }

  // final FC + sigmoid; h_T lives in buffer 0 after 512 steps
  if (b == 0 && t < 64) {
    const u16* hT = hbuf + (t << 10);
    float a = fc_b[0];
    for (int k = 0; k < 1024; k += 8) {
      bf16x8 hv = *(const bf16x8*)(hT + k);
#pragma unroll
      for (int j = 0; j < 8; ++j) a += (float)hv[j] * fc_w[k + j];
    }
    out[t] = sigm(a);
  }
}

// ---------- launch ----------
extern "C" void kernel_launch(void* const* d_in, const int* in_sizes, int n_in,
                              void* d_out, int out_size, void* d_ws, size_t ws_size,
                              hipStream_t stream) {
  const float* x    = (const float*)d_in[0];
  const float* w_ih = (const float*)d_in[1];
  const float* w_hh = (const float*)d_in[2];
  const float* b_ih = (const float*)d_in[3];
  const float* b_hh = (const float*)d_in[4];
  const float* fc_w = (const float*)d_in[5];
  const float* fc_b = (const float*)d_in[6];
  float* out = (float*)d_out;

  // workspace layout (44.3 MB total)
  char* ws = (char*)d_ws;
  u16* xb   = (u16*)(ws);                      // 64*512*512*2  = 33,554,432
  u16* wib  = (u16*)(ws + 33554432);           // 4096*512*2    =  4,194,304
  u16* whb  = (u16*)(ws + 37748736);           // 4096*1024*2   =  8,388,608
  u16* hbuf = (u16*)(ws + 46137344);           // 2*64*1024*2   =    262,144

  cvt_x_transpose<<<8192, 256, 0, stream>>>(x, xb);
  cvt_f32_bf16_v4<<<512, 256, 0, stream>>>(w_ih, wib, 2097152 / 4);
  cvt_f32_bf16_v4<<<1024, 256, 0, stream>>>(w_hh, whb, 4194304 / 4);

  void* args[] = {(void*)&xb, (void*)&wib, (void*)&whb, (void*)&hbuf,
                  (void*)&b_ih, (void*)&b_hh, (void*)&fc_w, (void*)&fc_b, (void*)&out};
  hipLaunchCooperativeKernel((void*)lstm_seq, dim3(128), dim3(256), args, 0, stream);
}

// Round 3
// 4672.215 us; speedup vs baseline: 2.7159x; 2.7159x over previous
//
#include <hip/hip_runtime.h>
#include <hip/hip_bf16.h>

typedef __bf16 bf16x8 __attribute__((ext_vector_type(8)));
typedef float f32x4 __attribute__((ext_vector_type(4)));
typedef unsigned int u32x4 __attribute__((ext_vector_type(4)));
typedef unsigned short u16;
typedef unsigned int u32;

// ---------- helpers ----------
__device__ __forceinline__ u16 f2bf(float f) {
  union { float f; unsigned int i; } c;
  c.f = f;
  unsigned int x = c.i;
  return (u16)((x + 0x7fffu + ((x >> 16) & 1u)) >> 16);  // RNE
}
__device__ __forceinline__ float sigm(float x) { return 1.f / (1.f + __expf(-x)); }
__device__ __forceinline__ float tanh_fast(float x) {
  float e2 = __expf(2.f * x);
  return 1.f - 2.f / (e2 + 1.f);
}

// coherent (cross-XCD) 2-byte store: write-through past L2
__device__ __forceinline__ void st_b16_sc(u16* addr, u32 val) {
  asm volatile("global_store_short %0, %1, off sc0 sc1" :: "v"(addr), "v"(val) : "memory");
}
// coherent 4-byte load (spin polling)
__device__ __forceinline__ u32 ld_u32_sc(const u32* p) {
  u32 v;
  asm volatile("global_load_dword %0, %1, off sc0 sc1\n\ts_waitcnt vmcnt(0)"
               : "=v"(v) : "v"(p) : "memory");
  return v;
}

// ---------- fp32 -> bf16 (vectorized) ----------
__global__ void cvt_f32_bf16_v4(const float* __restrict__ in, u16* __restrict__ out, int n4) {
  int stride = gridDim.x * blockDim.x;
  for (int i = blockIdx.x * blockDim.x + threadIdx.x; i < n4; i += stride) {
    float4 v = reinterpret_cast<const float4*>(in)[i];
    union { u16 u[4]; uint2 d; } o;
    o.u[0] = f2bf(v.x); o.u[1] = f2bf(v.y); o.u[2] = f2bf(v.z); o.u[3] = f2bf(v.w);
    reinterpret_cast<uint2*>(out)[i] = o.d;
  }
}

// ---------- x: [N=64][T=512][d=512] f32 -> [T][N][d] bf16 (+ ctr reset) ----------
__global__ void cvt_x_transpose(const float* __restrict__ in, u16* __restrict__ out,
                                u32* __restrict__ ctr) {
  if (blockIdx.x == 0 && threadIdx.x == 0) ctr[0] = 0u;
  int i = blockIdx.x * blockDim.x + threadIdx.x;
  if (i >= 64 * 512 * 64) return;
  int k8 = i & 63, t = (i >> 6) & 511, n = i >> 15;
  const float* src = in + ((size_t)(n * 512 + t) << 9) + (k8 << 3);
  float4 a = reinterpret_cast<const float4*>(src)[0];
  float4 b = reinterpret_cast<const float4*>(src)[1];
  union { u16 u[8]; uint4 d; } o;
  o.u[0] = f2bf(a.x); o.u[1] = f2bf(a.y); o.u[2] = f2bf(a.z); o.u[3] = f2bf(a.w);
  o.u[4] = f2bf(b.x); o.u[5] = f2bf(b.y); o.u[6] = f2bf(b.z); o.u[7] = f2bf(b.w);
  *reinterpret_cast<uint4*>(out + ((size_t)(t * 64 + n) << 9) + (k8 << 3)) = o.d;
}

// ---------- persistent LSTM: 128 blocks x 256 threads, 8 hidden units/block ----------
__global__ void __launch_bounds__(256, 1) lstm_seq(
    const u16* __restrict__ xb,     // [512][64][512] bf16
    const u16* __restrict__ wib,    // [4096][512] bf16
    const u16* __restrict__ whb,    // [4096][1024] bf16
    u16* __restrict__ hbuf,         // [2][64][1024] bf16
    float* __restrict__ hTf,        // [64][1024] f32 (final h)
    u32* __restrict__ ctr,          // barrier counter (monotonic)
    const float* __restrict__ b_ih, const float* __restrict__ b_hh) {
  __shared__ u16 wh[32][1040];     // stride 1040 u16 = 520 dw (4-way banks)
  __shared__ u16 wi[32][528];      // stride 528 u16 = 264 dw

  int b = blockIdx.x, t = threadIdx.x;
  int j0 = b << 3;

  // stage weight slices (once)
  for (int idx = t; idx < 32 * 128; idx += 256) {
    int l = idx >> 7, c8 = idx & 127;
    int gr = ((l >> 3) << 10) + j0 + (l & 7);
    *(bf16x8*)(&wh[l][c8 * 8]) = *(const bf16x8*)(whb + ((size_t)gr << 10) + c8 * 8);
  }
  for (int idx = t; idx < 32 * 64; idx += 256) {
    int l = idx >> 6, c8 = idx & 63;
    int gr = ((l >> 3) << 10) + j0 + (l & 7);
    *(bf16x8*)(&wi[l][c8 * 8]) = *(const bf16x8*)(wib + ((size_t)gr << 9) + c8 * 8);
  }

  int lane = t & 63, wave = t >> 6;
  int m0 = wave << 4;
  int lr = lane & 15, hi = lane >> 4, lk8 = hi << 3;
  int u = lane & 7;

  // per-lane biases (u = lane&7)
  float bi_r = b_ih[j0 + u]        + b_hh[j0 + u];
  float bf_r = b_ih[1024 + j0 + u] + b_hh[1024 + j0 + u];
  float bg_r = b_ih[2048 + j0 + u] + b_hh[2048 + j0 + u];
  float bo_r = b_ih[3072 + j0 + u] + b_hh[3072 + j0 + u];
  float c_[4] = {0.f, 0.f, 0.f, 0.f};

  __syncthreads();

  f32x4 acc[2];
  auto xgemm = [&](int step) {
    acc[0] = (f32x4){0.f, 0.f, 0.f, 0.f};
    acc[1] = (f32x4){0.f, 0.f, 0.f, 0.f};
    const u16* xbase = xb + ((size_t)step << 15) + ((m0 + lr) << 9) + lk8;
#pragma unroll
    for (int kk = 0; kk < 16; ++kk) {
      bf16x8 a = *(const bf16x8*)(xbase + kk * 32);
      bf16x8 w0 = *(const bf16x8*)(&wi[lr][kk * 32 + lk8]);
      bf16x8 w1 = *(const bf16x8*)(&wi[16 + lr][kk * 32 + lk8]);
      acc[0] = __builtin_amdgcn_mfma_f32_16x16x32_bf16(a, w0, acc[0], 0, 0, 0);
      acc[1] = __builtin_amdgcn_mfma_f32_16x16x32_bf16(a, w1, acc[1], 0, 0, 0);
    }
  };

  xgemm(0);
  u32 target = 0;

  for (int s = 0; s < 512; ++s) {
    if (s > 0) {
      // h-GEMM: coherent batched loads of this wave's 16 h rows, then MFMA
      const u16* hr = hbuf + ((s & 1) << 16);
      const u16* hbase = hr + ((m0 + lr) << 10) + lk8;
      u32x4 ha[32];
#define LDH(OFF) asm volatile("global_load_dwordx4 %0, %1, off offset:" #OFF " sc0 sc1" \
                              : "=v"(ha[OFF / 64]) : "v"(hbase));
      LDH(0) LDH(64) LDH(128) LDH(192) LDH(256) LDH(320) LDH(384) LDH(448)
      LDH(512) LDH(576) LDH(640) LDH(704) LDH(768) LDH(832) LDH(896) LDH(960)
      LDH(1024) LDH(1088) LDH(1152) LDH(1216) LDH(1280) LDH(1344) LDH(1408) LDH(1472)
      LDH(1536) LDH(1600) LDH(1664) LDH(1728) LDH(1792) LDH(1856) LDH(1920) LDH(1984)
#undef LDH
      asm volatile("s_waitcnt vmcnt(0)" ::: "memory");
      __builtin_amdgcn_sched_barrier(0);
#pragma unroll
      for (int kk = 0; kk < 32; ++kk) {
        union { u32x4 u; bf16x8 v; } av; av.u = ha[kk];
        bf16x8 w0 = *(const bf16x8*)(&wh[lr][kk * 32 + lk8]);
        bf16x8 w1 = *(const bf16x8*)(&wh[16 + lr][kk * 32 + lk8]);
        acc[0] = __builtin_amdgcn_mfma_f32_16x16x32_bf16(av.v, w0, acc[0], 0, 0, 0);
        acc[1] = __builtin_amdgcn_mfma_f32_16x16x32_bf16(av.v, w1, acc[1], 0, 0, 0);
      }
    }

    // pointwise cell update fully in registers (lane pairs via shfl_xor 8)
    u16* hw = hbuf + (((s + 1) & 1) << 16);
#pragma unroll
    for (int q = 0; q < 4; ++q) {
      float a0 = acc[0][q], a1 = acc[1][q];
      float p0 = __shfl_xor(a0, 8, 64);   // f for lr<8
      float p1 = __shfl_xor(a1, 8, 64);   // o for lr<8
      if (lr < 8) {
        float gi = a0 + bi_r, gf = p0 + bf_r, gg = a1 + bg_r, go = p1 + bo_r;
        float ii = sigm(gi), ff = sigm(gf), tg = tanh_fast(gg), oo = sigm(go);
        float cn = ff * c_[q] + ii * tg;
        c_[q] = cn;
        float hv = oo * tanh_fast(cn);
        int m = m0 + (hi << 2) + q;
        if (s == 511) {
          hTf[(m << 10) + j0 + u] = hv;          // plain store; kernel-end flush
        } else {
          st_b16_sc(hw + (m << 10) + j0 + u, (u32)f2bf(hv));
        }
      }
    }

    if (s < 511) {
      asm volatile("s_waitcnt vmcnt(0)" ::: "memory");   // h stores at coherence point
      __syncthreads();
      if (t == 0)
        __hip_atomic_fetch_add(ctr, 1u, __ATOMIC_RELAXED, __HIP_MEMORY_SCOPE_AGENT);
      target += 128;
      xgemm(s + 1);                                      // overlap with barrier latency
      if (t == 0) {
        while (ld_u32_sc(ctr) < target) __builtin_amdgcn_s_sleep(1);
      }
      __syncthreads();
    }
  }
}

// ---------- FC head: block n computes out[n] ----------
__global__ void fc_head(const float* __restrict__ hTf, const float* __restrict__ fc_w,
                        const float* __restrict__ fc_b, float* __restrict__ out) {
  __shared__ float red[4];
  int n = blockIdx.x, t = threadIdx.x;
  float4 hv = *(const float4*)(hTf + (n << 10) + t * 4);
  float4 wv = *(const float4*)(fc_w + t * 4);
  float s = hv.x * wv.x + hv.y * wv.y + hv.z * wv.z + hv.w * wv.w;
#pragma unroll
  for (int o = 32; o; o >>= 1) s += __shfl_down(s, o, 64);
  if ((t & 63) == 0) red[t >> 6] = s;
  __syncthreads();
  if (t == 0) out[n] = sigm(red[0] + red[1] + red[2] + red[3] + fc_b[0]);
}

// ---------- launch ----------
extern "C" void kernel_launch(void* const* d_in, const int* in_sizes, int n_in,
                              void* d_out, int out_size, void* d_ws, size_t ws_size,
                              hipStream_t stream) {
  const float* x    = (const float*)d_in[0];
  const float* w_ih = (const float*)d_in[1];
  const float* w_hh = (const float*)d_in[2];
  const float* b_ih = (const float*)d_in[3];
  const float* b_hh = (const float*)d_in[4];
  const float* fc_w = (const float*)d_in[5];
  const float* fc_b = (const float*)d_in[6];
  float* out = (float*)d_out;

  char* ws = (char*)d_ws;
  u16*   xb   = (u16*)(ws);                    // 33,554,432 B
  u16*   wib  = (u16*)(ws + 33554432);         //  4,194,304 B
  u16*   whb  = (u16*)(ws + 37748736);         //  8,388,608 B
  u16*   hbuf = (u16*)(ws + 46137344);         //    262,144 B
  float* hTf  = (float*)(ws + 46399488);       //    262,144 B
  u32*   ctr  = (u32*)(ws + 46661632);         //        256 B

  cvt_x_transpose<<<8192, 256, 0, stream>>>(x, xb, ctr);
  cvt_f32_bf16_v4<<<512, 256, 0, stream>>>(w_ih, wib, 2097152 / 4);
  cvt_f32_bf16_v4<<<1024, 256, 0, stream>>>(w_hh, whb, 4194304 / 4);

  lstm_seq<<<128, 256, 0, stream>>>(xb, wib, whb, hbuf, hTf, ctr, b_ih, b_hh);
  fc_head<<<64, 256, 0, stream>>>(hTf, fc_w, fc_b, out);
}